// Round 1
// 333.072 us; speedup vs baseline: 1.0308x; 1.0308x over previous
//
#include <hip/hip_runtime.h>

#define N_  8
#define C_  32
#define H_  224
#define W_  224
#define TM_ 4
#define TA  32   // output tile extent along a (rows)
#define TB  32   // output tile extent along b (cols)
#define NC  4    // n processed per LDS pass (halves LDS -> 8 blocks/CU)

// Block = 256 threads handles one (c, 32x32 output tile) for ALL t (4) and n (8).
// Compute phase: lanes along a  -> sample x consecutive per lane -> coalesced gathers.
// Write  phase: lanes along b  -> coalesced float4 stores (via LDS transpose tile).
// n is processed in 2 chunks of 4 so the LDS tile is 16896 B: 8 blocks/CU resident,
// entire 1568-block grid co-resident (no dispatch tail). Gather indices are
// n-independent and live in registers across both chunks.
// Reference quirk preserved: hx = xs[a], hy = ys[b]; out channel = c*TM + t.
__global__ __launch_bounds__(256, 8) void persp_kernel(
    const float* __restrict__ inp,   // (N, C, H, W)
    const float* __restrict__ wt,    // (TM, C, 8)
    float* __restrict__ out)         // (N, C*TM, H, W)
{
    __shared__ float tile[NC][TA][TB + 1];   // +1 pad: conflict-free transpose

    const int tid = threadIdx.x;
    const int c   = blockIdx.y;
    const int ta  = blockIdx.x / (W_ / TB);
    const int tb  = blockIdx.x % (W_ / TB);
    const int a0  = ta * TA;
    const int b0  = tb * TB;

    // compute-phase mapping: lane -> a, group -> b
    const int a_off = tid & 31;        // 0..31 along a (fast, per half-wave)
    const int bgrp  = tid >> 5;        // 0..7
    const int a     = a0 + a_off;

    const float step = 2.0f / 223.0f;  // linspace(-1,1,224) step
    const float hx   = -1.0f + (float)a * step;   // xs[a]

    // write-phase mapping: lane -> 4 consecutive b (float4), group -> a rows
    const int j4 = (tid & 7) * 4;      // 0,4,...,28 along b
    const int iw = tid >> 3;           // 0..31 along a

    const size_t plane   = (size_t)H_ * W_;
    const size_t istride = (size_t)C_ * plane;         // per-n input stride
    const size_t ostride = (size_t)(C_ * TM_) * plane; // per-n output stride

    const float* ibase = inp + (size_t)c * plane;

    for (int t = 0; t < TM_; ++t) {
        const float* th = wt + ((size_t)t * C_ + c) * 8;
        const float t0 = th[0], t1 = th[1], t2 = th[2], t3 = th[3];
        const float t4 = th[4], t5 = th[5], t6 = th[6], t7 = th[7];

        int   iA[4], iB[4], iC[4], iD[4];
        float wa[4], wb[4], wc[4], wd[4];

#pragma unroll
        for (int p = 0; p < 4; ++p) {
            const int b = b0 + bgrp + 8 * p;
            const float hy = -1.0f + (float)b * step;  // ys[b]

            const float w0 = t0 * hx + t1 * hy + t2;
            const float w1 = t3 * hx + t4 * hy + t5;
            const float w2 = t6 * hx + t7 * hy + 1.0f;

            const float xs = w0 / w2;
            const float ys = w1 / w2;

            const float x = 0.5f * ((xs + 1.0f) * 222.0f);
            const float y = 0.5f * ((ys + 1.0f) * 222.0f);

            int x0i = (int)floorf(x);
            int y0i = (int)floorf(y);
            int x1i = x0i + 1;
            int y1i = y0i + 1;
            x0i = min(max(x0i, 0), W_ - 1);
            x1i = min(max(x1i, 0), W_ - 1);
            y0i = min(max(y0i, 0), H_ - 1);
            y1i = min(max(y1i, 0), H_ - 1);

            const float x0f = (float)x0i, x1f = (float)x1i;
            const float y0f = (float)y0i, y1f = (float)y1i;

            wa[p] = (x1f - x) * (y1f - y);
            wb[p] = (x1f - x) * (y1f - y0f);
            wc[p] = (x - x0f) * (y1f - y);
            wd[p] = (x - x0f) * (y - y0f);

            iA[p] = y0i * W_ + x0i;
            iB[p] = y1i * W_ + x0i;
            iC[p] = y0i * W_ + x1i;
            iD[p] = y1i * W_ + x1i;
        }

#pragma unroll
        for (int nh = 0; nh < N_ / NC; ++nh) {
            // gather phase: 4 n-planes, indices reused from registers
#pragma unroll
            for (int nn = 0; nn < NC; ++nn) {
                const int n = nh * NC + nn;
                const float* ib = ibase + (size_t)n * istride;
#pragma unroll
                for (int p = 0; p < 4; ++p) {
                    const float Ia = ib[iA[p]];
                    const float Ib = ib[iB[p]];
                    const float Ic = ib[iC[p]];
                    const float Id = ib[iD[p]];
                    tile[nn][a_off][bgrp + 8 * p] =
                        wa[p] * Ia + wb[p] * Ib + wc[p] * Ic + wd[p] * Id;
                }
            }
            __syncthreads();

            // coalesced float4 write-out: lanes along b
#pragma unroll
            for (int nn = 0; nn < NC; ++nn) {
                const int n = nh * NC + nn;
                float4 v;
                v.x = tile[nn][iw][j4 + 0];
                v.y = tile[nn][iw][j4 + 1];
                v.z = tile[nn][iw][j4 + 2];
                v.w = tile[nn][iw][j4 + 3];
                float* op = out + (size_t)n * ostride
                                + ((size_t)(c * TM_ + t)) * plane
                                + (size_t)(a0 + iw) * W_ + (b0 + j4);
                *reinterpret_cast<float4*>(op) = v;
            }
            __syncthreads();
        }
    }
}

extern "C" void kernel_launch(void* const* d_in, const int* in_sizes, int n_in,
                              void* d_out, int out_size, void* d_ws, size_t ws_size,
                              hipStream_t stream) {
    const float* inp = (const float*)d_in[0];   // (8,32,224,224) f32
    const float* wt  = (const float*)d_in[1];   // (4,32,8) f32
    float* out = (float*)d_out;                 // (8,128,224,224) f32

    dim3 grid((H_ / TA) * (W_ / TB), C_);       // 49 x 32 = 1568 blocks
    persp_kernel<<<grid, 256, 0, stream>>>(inp, wt, out);
}